// Round 3
// baseline (1051.025 us; speedup 1.0000x reference)
//
#include <hip/hip_runtime.h>
#include <stdint.h>

#define NNODES 20000
#define NEDGES 400000
// DIM=128, NB=16, ZD=16, NSPEC=51, NLAYERS=2, N_ONSITE=3, CUTOFF=5.0

__device__ __forceinline__ float bf2f(uint16_t u){ return __uint_as_float(((uint32_t)u)<<16); }
__device__ __forceinline__ uint16_t f2bf(float f){
  uint32_t x = __float_as_uint(f);
  x += 0x7FFFu + ((x>>16)&1u);          // round-to-nearest-even
  return (uint16_t)(x>>16);
}
__device__ __forceinline__ float siluf(float x){ return x/(1.0f+__expf(-x)); }
__device__ __forceinline__ float ldf(const void* p, int i, int md){
  return (md==1) ? bf2f(((const uint16_t*)p)[i]) : ((const float*)p)[i];
}

// converted-weights layout (float elements within conv buffer)
#define OFF_V0   0
#define N_V0     32768
#define OFF_WS1  32768
#define N_WS1    16384
#define OFF_BS1  49152
#define N_BS1    128
#define OFF_V1   49280
#define N_V1     262144
#define OFF_WA   311424
#define N_WA     98304
#define OFF_BA   409728
#define N_BA     768
#define OFF_WB   410496
#define N_WB     98304
#define OFF_BB   508800
#define N_BB     768
#define N_CONV   509568

// ---------------- dtype probe: distances known to be in [0.8, 5.0] ----------------
__global__ void k_probe(const void* dist, int* mode){
  if(threadIdx.x != 0 || blockIdx.x != 0) return;
  const float* f = (const float*)dist;
  const uint16_t* h = (const uint16_t*)dist;
  int okf = 1, okb = 1;
  for(int i=0;i<256;i++){
    float a = f[i];       okf &= (a >= 0.7f) & (a <= 5.1f);
    float b = bf2f(h[i]); okb &= (b >= 0.7f) & (b <= 5.1f);
  }
  *mode = okb ? 1 : (okf ? 0 : 1);   // 1 = bf16 inputs/outputs, 0 = fp32
}

// ---------------- convert all weight tensors to fp32 in workspace ----------------
__global__ __launch_bounds__(256) void k_conv(const void* s0,const void* s1,const void* s2,const void* s3,
                                              const void* s4,const void* s5,const void* s6,const void* s7,
                                              const int* __restrict__ modep, float* __restrict__ dst){
  int md = *modep;
  int i = blockIdx.x*256 + threadIdx.x;
  if(i >= N_CONV) return;
  const void* src; int t = i;
  if(t < N_V0){src=s0;}
  else if((t-=N_V0) < N_WS1){src=s1;}
  else if((t-=N_WS1) < N_BS1){src=s2;}
  else if((t-=N_BS1) < N_V1){src=s3;}
  else if((t-=N_V1) < N_WA){src=s4;}
  else if((t-=N_WA) < N_BA){src=s5;}
  else if((t-=N_BA) < N_WB){src=s6;}
  else {t-=N_WB; src=s7;}
  dst[i] = ldf(src, t, md);
}

// ---------------- edge radial basis * switch -> G[e][16] (fp32) ----------------
__global__ __launch_bounds__(256) void k_G(const void* __restrict__ dist,
                                           const void* __restrict__ sw,
                                           const int* __restrict__ modep,
                                           float* __restrict__ G){
  int e = blockIdx.x*256 + threadIdx.x;
  if(e >= NEDGES) return;
  int md = *modep;
  float r = ldf(dist, e, md);
  float w = ldf(sw, e, md);
  float rinv = 1.0f/r;
  const float sigma = 0.8f/15.0f;
  const float isig  = 15.0f/0.8f;
  float v[16];
  #pragma unroll
  for(int b=0;b<16;b++){
    float mu = 0.2f + sigma*(float)b;
    float t = (rinv-mu)*isig;
    v[b] = w*__expf(-0.5f*t*t);
  }
  float4* o = (float4*)(G + (size_t)e*16);
  o[0] = make_float4(v[0],v[1],v[2],v[3]);
  o[1] = make_float4(v[4],v[5],v[6],v[7]);
  o[2] = make_float4(v[8],v[9],v[10],v[11]);
  o[3] = make_float4(v[12],v[13],v[14],v[15]);
}

// ---------------- CSR build over edge_src ----------------
__global__ __launch_bounds__(256) void k_hist(const int* __restrict__ src, int* __restrict__ cnt){
  int e = blockIdx.x*256 + threadIdx.x;
  if(e < NEDGES){
    int s = src[e];
    if((unsigned)s < NNODES) atomicAdd(&cnt[s], 1);
  }
}

// single wave: no inter-wave sync needed
__global__ __launch_bounds__(64) void k_scan(int* cnt_cur, int* offs){
  int t = threadIdx.x;
  const int chunk = (NNODES + 63)/64;   // 313
  int lo = t*chunk, hi = lo+chunk;
  if(lo > NNODES) lo = NNODES;
  if(hi > NNODES) hi = NNODES;
  int s = 0;
  for(int i=lo;i<hi;i++) s += cnt_cur[i];
  int v = s;
  #pragma unroll
  for(int d=1; d<64; d<<=1){
    int u = __shfl_up(v, d);
    if(t >= d) v += u;
  }
  int run = v - s;   // exclusive prefix of this chunk
  for(int i=lo;i<hi;i++){
    int c = cnt_cur[i];
    offs[i] = run;
    cnt_cur[i] = run;    // cursor for fill
    run += c;
  }
  if(t==63) offs[NNODES] = run;  // = NEDGES
}

__global__ __launch_bounds__(256) void k_fill(const int* __restrict__ src, int* __restrict__ cur,
                                              int* __restrict__ perm){
  int e = blockIdx.x*256 + threadIdx.x;
  if(e >= NEDGES) return;
  int s = src[e];
  if((unsigned)s >= NNODES) return;
  int p = atomicAdd(&cur[s], 1);
  if((unsigned)p < NEDGES) perm[p] = e;
}

// ---------------- species tables: ZWs0[s][128] fp32, Zf[s][16] fp32 ----------------
__global__ __launch_bounds__(128) void k_spec(const void* __restrict__ Z,
                                              const void* __restrict__ Ws0,
                                              const void* __restrict__ bs0,
                                              const int* __restrict__ modep,
                                              float* __restrict__ ZWs0,
                                              float* __restrict__ Zf){
  int s = blockIdx.x, d = threadIdx.x;
  int md = *modep;
  float zk[16];
  #pragma unroll
  for(int k=0;k<16;k++) zk[k] = ldf(Z, s*16+k, md);
  float a = ldf(bs0, d, md);
  #pragma unroll
  for(int k=0;k<16;k++) a = fmaf(zk[k], ldf(Ws0, k*128+d, md), a);
  ZWs0[s*128+d] = a;
  if(d < 16) Zf[s*16+d] = zk[d];
}

// ---------------- layer-0 message: T0[n][b][zk] = sum_e g[b]*Zf[spd][zk]; msg = T0@V0 ----
__global__ __launch_bounds__(256) void k_msg0(const int* __restrict__ offs,
                                              const int* __restrict__ perm,
                                              const int* __restrict__ edst,
                                              const int* __restrict__ species,
                                              const float* __restrict__ G,
                                              const float* __restrict__ Zf,
                                              const float* __restrict__ V0,   // fp32 converted
                                              const float* __restrict__ ZWs0,
                                              float* __restrict__ zi){
  __shared__ float T0[8*256];     // 8 KB
  __shared__ float P[4*8*128];    // 16 KB
  int w = threadIdx.x>>6, lane = threadIdx.x&63;
  int n0 = blockIdx.x*8;
  int bq = lane>>2, zk0 = (lane&3)*4;
  for(int sub=0; sub<2; sub++){
    int ln = w*2+sub, n = n0+ln;
    float4 t = make_float4(0.f,0.f,0.f,0.f);
    int beg = offs[n], end = offs[n+1];
    for(int ei=beg; ei<end; ei++){
      int e = perm[ei];
      if((unsigned)e >= NEDGES) continue;
      int dn = edst[e];
      if((unsigned)dn >= NNODES) continue;
      int sp = species[dn];
      if((unsigned)sp >= 51) continue;
      float g = G[(size_t)e*16 + bq];
      float4 z4 = *(const float4*)(Zf + sp*16 + zk0);
      t.x = fmaf(g, z4.x, t.x); t.y = fmaf(g, z4.y, t.y);
      t.z = fmaf(g, z4.z, t.z); t.w = fmaf(g, z4.w, t.w);
    }
    *(float4*)(&T0[ln*256 + bq*16 + zk0]) = t;
  }
  __syncthreads();
  int d0 = lane*2;
  float2 acc[8];
  #pragma unroll
  for(int n=0;n<8;n++) acc[n] = make_float2(0.f,0.f);
  for(int r=w*64; r<w*64+64; r+=4){
    float2 v0 = *(const float2*)(&V0[(size_t)(r+0)*128 + d0]);
    float2 v1 = *(const float2*)(&V0[(size_t)(r+1)*128 + d0]);
    float2 v2 = *(const float2*)(&V0[(size_t)(r+2)*128 + d0]);
    float2 v3 = *(const float2*)(&V0[(size_t)(r+3)*128 + d0]);
    #pragma unroll
    for(int n=0;n<8;n++){
      float4 t4 = *(const float4*)(&T0[n*256 + r]);
      acc[n].x = fmaf(t4.x, v0.x, acc[n].x); acc[n].y = fmaf(t4.x, v0.y, acc[n].y);
      acc[n].x = fmaf(t4.y, v1.x, acc[n].x); acc[n].y = fmaf(t4.y, v1.y, acc[n].y);
      acc[n].x = fmaf(t4.z, v2.x, acc[n].x); acc[n].y = fmaf(t4.z, v2.y, acc[n].y);
      acc[n].x = fmaf(t4.w, v3.x, acc[n].x); acc[n].y = fmaf(t4.w, v3.y, acc[n].y);
    }
  }
  #pragma unroll
  for(int n=0;n<8;n++) *(float2*)(&P[(w*8+n)*128 + d0]) = acc[n];
  __syncthreads();
  for(int i=threadIdx.x; i<512; i+=256){
    int n = i>>6, dp = (i&63)*2;
    int node = n0+n;
    int sp = species[node];
    if((unsigned)sp >= 51) sp = 0;
    float2 a0 = *(float2*)(&P[n*128+dp]);
    float2 a1 = *(float2*)(&P[(8+n)*128+dp]);
    float2 a2 = *(float2*)(&P[(16+n)*128+dp]);
    float2 a3 = *(float2*)(&P[(24+n)*128+dp]);
    float2 zs = *(const float2*)(&ZWs0[sp*128+dp]);
    float x = a0.x+a1.x+a2.x+a3.x+zs.x;
    float y = a0.y+a1.y+a2.y+a3.y+zs.y;
    *(float2*)(&zi[(size_t)node*128+dp]) = make_float2(siluf(x), siluf(y));
  }
}

// ---------------- layer-1 message: T[n][b][k] = sum_e g[b]*zi[dst][k]; msg = T@V1 ----
__global__ __launch_bounds__(256) void k_msg1(const int* __restrict__ offs,
                                              const int* __restrict__ perm,
                                              const int* __restrict__ edst,
                                              const float* __restrict__ zi,
                                              const float* __restrict__ G,
                                              const float* __restrict__ V1,   // fp32 converted
                                              float* __restrict__ zacc){
  __shared__ float T[8*2048];     // 64 KB
  __shared__ float P[4*8*128];    // 16 KB
  int w = threadIdx.x>>6, lane = threadIdx.x&63;
  int n0 = blockIdx.x*8;
  int k0 = lane*2;
  for(int sub=0; sub<2; sub++){
    int ln = w*2+sub, n = n0+ln;
    float2 t[16];
    #pragma unroll
    for(int b=0;b<16;b++) t[b] = make_float2(0.f,0.f);
    int beg = offs[n], end = offs[n+1];
    for(int ei=beg; ei<end; ei++){
      int e = perm[ei];
      if((unsigned)e >= NEDGES) continue;
      int dn = edst[e];
      if((unsigned)dn >= NNODES) continue;
      float2 z2 = *(const float2*)(zi + (size_t)dn*128 + k0);
      const float4* gp = (const float4*)(G + (size_t)e*16);
      float4 g0 = gp[0], g1 = gp[1], g2 = gp[2], g3 = gp[3];
      float gv[16] = {g0.x,g0.y,g0.z,g0.w, g1.x,g1.y,g1.z,g1.w,
                      g2.x,g2.y,g2.z,g2.w, g3.x,g3.y,g3.z,g3.w};
      #pragma unroll
      for(int b=0;b<16;b++){
        t[b].x = fmaf(gv[b], z2.x, t[b].x);
        t[b].y = fmaf(gv[b], z2.y, t[b].y);
      }
    }
    #pragma unroll
    for(int b=0;b<16;b++) *(float2*)(&T[ln*2048 + b*128 + k0]) = t[b];
  }
  __syncthreads();
  int d0 = lane*2;
  float2 acc[8];
  #pragma unroll
  for(int n=0;n<8;n++) acc[n] = make_float2(0.f,0.f);
  for(int r=w*512; r<w*512+512; r+=4){
    float2 v0 = *(const float2*)(&V1[(size_t)(r+0)*128 + d0]);
    float2 v1 = *(const float2*)(&V1[(size_t)(r+1)*128 + d0]);
    float2 v2 = *(const float2*)(&V1[(size_t)(r+2)*128 + d0]);
    float2 v3 = *(const float2*)(&V1[(size_t)(r+3)*128 + d0]);
    #pragma unroll
    for(int n=0;n<8;n++){
      float4 t4 = *(const float4*)(&T[n*2048 + r]);
      acc[n].x = fmaf(t4.x, v0.x, acc[n].x); acc[n].y = fmaf(t4.x, v0.y, acc[n].y);
      acc[n].x = fmaf(t4.y, v1.x, acc[n].x); acc[n].y = fmaf(t4.y, v1.y, acc[n].y);
      acc[n].x = fmaf(t4.z, v2.x, acc[n].x); acc[n].y = fmaf(t4.z, v2.y, acc[n].y);
      acc[n].x = fmaf(t4.w, v3.x, acc[n].x); acc[n].y = fmaf(t4.w, v3.y, acc[n].y);
    }
  }
  #pragma unroll
  for(int n=0;n<8;n++) *(float2*)(&P[(w*8+n)*128 + d0]) = acc[n];
  __syncthreads();
  for(int i=threadIdx.x; i<512; i+=256){
    int n = i>>6, dp = (i&63)*2;
    int node = n0+n;
    float2 a0 = *(float2*)(&P[n*128+dp]);
    float2 a1 = *(float2*)(&P[(8+n)*128+dp]);
    float2 a2 = *(float2*)(&P[(16+n)*128+dp]);
    float2 a3 = *(float2*)(&P[(24+n)*128+dp]);
    float2 zs = *(float2*)(&zacc[(size_t)node*128+dp]);
    float x = a0.x+a1.x+a2.x+a3.x+zs.x;
    float y = a0.y+a1.y+a2.y+a3.y+zs.y;
    *(float2*)(&zacc[(size_t)node*128+dp]) = make_float2(siluf(x), siluf(y));
  }
}

// ---------------- zself1 = zi @ Ws1 + bs1 (wave per 4 nodes), fp32 weights ----------------
__global__ __launch_bounds__(256) void k_linear(const float* __restrict__ zi,
                                                const float* __restrict__ W,
                                                const float* __restrict__ bias,
                                                float* __restrict__ out){
  __shared__ float zT[4][512];
  int w = threadIdx.x>>6, lane = threadIdx.x&63;
  int n0 = blockIdx.x*16 + w*4;
  int d0 = lane*2;
  float* z = zT[w];
  #pragma unroll
  for(int i=0;i<8;i++){
    int idx = lane + 64*i; int ni = idx>>7; int k = idx&127;
    z[k*4+ni] = zi[(size_t)(n0+ni)*128 + k];
  }
  __syncthreads();
  float b0 = bias[d0], b1 = bias[d0+1];
  float2 acc[4];
  #pragma unroll
  for(int ni=0;ni<4;ni++) acc[ni] = make_float2(b0,b1);
  #pragma unroll 8
  for(int k=0;k<128;k++){
    float4 z4 = *(const float4*)(z + k*4);
    float2 wv = *(const float2*)(&W[(size_t)k*128 + d0]);
    acc[0].x = fmaf(z4.x, wv.x, acc[0].x); acc[0].y = fmaf(z4.x, wv.y, acc[0].y);
    acc[1].x = fmaf(z4.y, wv.x, acc[1].x); acc[1].y = fmaf(z4.y, wv.y, acc[1].y);
    acc[2].x = fmaf(z4.z, wv.x, acc[2].x); acc[2].y = fmaf(z4.z, wv.y, acc[2].y);
    acc[3].x = fmaf(z4.w, wv.x, acc[3].x); acc[3].y = fmaf(z4.w, wv.y, acc[3].y);
  }
  #pragma unroll
  for(int ni=0;ni<4;ni++)
    *(float2*)(out + (size_t)(n0+ni)*128 + d0) = acc[ni];
}

// ---------------- onsite: 3 x (h=silu(z@Wa+ba); z+=h@Wb+bb), fp32 weights ----------------
__global__ __launch_bounds__(256) void k_onsite(float* __restrict__ zi,
                                                const float* __restrict__ Wa,
                                                const float* __restrict__ ba,
                                                const float* __restrict__ Wb,
                                                const float* __restrict__ bb,
                                                void* __restrict__ outb,
                                                long off1, int st1,
                                                long off2, int st2,
                                                const int* __restrict__ modep){
  __shared__ float zT[4][512];
  __shared__ float hT[4][512];
  int w = threadIdx.x>>6, lane = threadIdx.x&63;
  int n0 = blockIdx.x*16 + w*4;
  int d0 = lane*2;
  int md = *modep;
  float* z = zT[w];
  float* h = hT[w];
  #pragma unroll
  for(int i=0;i<8;i++){
    int idx = lane + 64*i; int ni = idx>>7; int k = idx&127;
    z[k*4+ni] = zi[(size_t)(n0+ni)*128 + k];
  }
  __syncthreads();
  for(int j=0;j<3;j++){
    const float* Wap = Wa + (size_t)j*16384;
    float a0 = ba[j*128+d0], a1 = ba[j*128+d0+1];
    float2 acc[4];
    #pragma unroll
    for(int ni=0;ni<4;ni++) acc[ni] = make_float2(a0,a1);
    #pragma unroll 8
    for(int k=0;k<128;k++){
      float4 z4 = *(const float4*)(z + k*4);
      float2 wv = *(const float2*)(&Wap[(size_t)k*128 + d0]);
      acc[0].x = fmaf(z4.x, wv.x, acc[0].x); acc[0].y = fmaf(z4.x, wv.y, acc[0].y);
      acc[1].x = fmaf(z4.y, wv.x, acc[1].x); acc[1].y = fmaf(z4.y, wv.y, acc[1].y);
      acc[2].x = fmaf(z4.z, wv.x, acc[2].x); acc[2].y = fmaf(z4.z, wv.y, acc[2].y);
      acc[3].x = fmaf(z4.w, wv.x, acc[3].x); acc[3].y = fmaf(z4.w, wv.y, acc[3].y);
    }
    __syncthreads();
    *(float4*)(h + d0*4)     = make_float4(siluf(acc[0].x), siluf(acc[1].x), siluf(acc[2].x), siluf(acc[3].x));
    *(float4*)(h + (d0+1)*4) = make_float4(siluf(acc[0].y), siluf(acc[1].y), siluf(acc[2].y), siluf(acc[3].y));
    __syncthreads();
    const float* Wbp = Wb + (size_t)j*16384;
    float c0 = bb[j*128+d0], c1 = bb[j*128+d0+1];
    float2 r[4];
    #pragma unroll
    for(int ni=0;ni<4;ni++)
      r[ni] = make_float2(z[d0*4+ni] + c0, z[(d0+1)*4+ni] + c1);
    #pragma unroll 8
    for(int k=0;k<128;k++){
      float4 h4 = *(const float4*)(h + k*4);
      float2 wv = *(const float2*)(&Wbp[(size_t)k*128 + d0]);
      r[0].x = fmaf(h4.x, wv.x, r[0].x); r[0].y = fmaf(h4.x, wv.y, r[0].y);
      r[1].x = fmaf(h4.y, wv.x, r[1].x); r[1].y = fmaf(h4.y, wv.y, r[1].y);
      r[2].x = fmaf(h4.z, wv.x, r[2].x); r[2].y = fmaf(h4.z, wv.y, r[2].y);
      r[3].x = fmaf(h4.w, wv.x, r[3].x); r[3].y = fmaf(h4.w, wv.y, r[3].y);
    }
    __syncthreads();
    *(float4*)(z + d0*4)     = make_float4(r[0].x, r[1].x, r[2].x, r[3].x);
    *(float4*)(z + (d0+1)*4) = make_float4(r[0].y, r[1].y, r[2].y, r[3].y);
    __syncthreads();
  }
  #pragma unroll
  for(int i=0;i<8;i++){
    int idx = lane + 64*i; int ni = idx>>7; int k = idx&127;
    int n = n0 + ni;
    float v = z[k*4+ni];
    zi[(size_t)n*128 + k] = v;
    if(md==1){
      uint16_t* ob = (uint16_t*)outb;
      uint16_t hb = f2bf(v);
      ob[off1 + (long)n*st1 + k] = hb;
      if(off2 >= 0) ob[off2 + (long)n*st2 + k] = hb;
    } else {
      float* ob = (float*)outb;
      ob[off1 + (long)n*st1 + k] = v;
      if(off2 >= 0) ob[off2 + (long)n*st2 + k] = v;
    }
  }
}

extern "C" void kernel_launch(void* const* d_in, const int* in_sizes, int n_in,
                              void* d_out, int out_size, void* d_ws, size_t ws_size,
                              hipStream_t stream){
  const int* species = (const int*)d_in[0];
  const int* esrc    = (const int*)d_in[1];
  const int* edst    = (const int*)d_in[2];
  const void* dist   = d_in[3];
  const void* swit   = d_in[4];
  const void* Z      = d_in[5];
  const void* Ws0    = d_in[6];
  const void* bs0    = d_in[7];
  const void* V0     = d_in[8];
  const void* Ws1    = d_in[9];
  const void* bs1    = d_in[10];
  const void* V1     = d_in[11];
  const void* Wa     = d_in[12];
  const void* ba     = d_in[13];
  const void* Wb     = d_in[14];
  const void* bb     = d_in[15];

  char* ws = (char*)d_ws;
  size_t off = 0;
  auto alloc = [&](size_t bytes)->void*{ void* p = ws + off; off = (off + bytes + 255) & ~(size_t)255; return p; };
  float* G    = (float*)alloc((size_t)NEDGES*16*4);     // 25.6 MB
  int*   offs = (int*)  alloc((size_t)(NNODES+1)*4);
  int*   cur  = (int*)  alloc((size_t)NNODES*4);
  int*   perm = (int*)  alloc((size_t)NEDGES*4);        // 1.6 MB
  float* zi   = (float*)alloc((size_t)NNODES*128*4);    // 10.24 MB
  float* zacc = (float*)alloc((size_t)NNODES*128*4);    // 10.24 MB
  float* ZWs0 = (float*)alloc((size_t)51*128*4);
  float* Zf   = (float*)alloc((size_t)51*16*4);
  float* conv = (float*)alloc((size_t)N_CONV*4);        // ~2.04 MB
  int*   mode = (int*)  alloc(256);
  // total ~50 MB

  const int EB = (NEDGES+255)/256;
  hipMemsetAsync(cur, 0, NNODES*4, stream);
  k_probe<<<1,64,0,stream>>>(dist, mode);
  k_conv <<<(N_CONV+255)/256,256,0,stream>>>(V0, Ws1, bs1, V1, Wa, ba, Wb, bb, mode, conv);
  k_G    <<<EB,256,0,stream>>>(dist, swit, mode, G);
  k_hist <<<EB,256,0,stream>>>(esrc, cur);
  k_scan <<<1,64,0,stream>>>(cur, offs);
  k_fill <<<EB,256,0,stream>>>(esrc, cur, perm);
  k_spec <<<51,128,0,stream>>>(Z, Ws0, bs0, mode, ZWs0, Zf);

  const long ZIS = (long)NNODES*128;   // element offset of zis block in d_out

  // layer 0
  k_msg0  <<<NNODES/8,256,0,stream>>>(offs, perm, edst, species, G, Zf, conv+OFF_V0, ZWs0, zi);
  k_onsite<<<NNODES/16,256,0,stream>>>(zi, conv+OFF_WA, conv+OFF_BA, conv+OFF_WB, conv+OFF_BB,
                                       d_out, ZIS, 256, (long)-1, 0, mode);

  // layer 1
  k_linear<<<NNODES/16,256,0,stream>>>(zi, conv+OFF_WS1, conv+OFF_BS1, zacc);
  k_msg1  <<<NNODES/8,256,0,stream>>>(offs, perm, edst, zi, G, conv+OFF_V1, zacc);
  k_onsite<<<NNODES/16,256,0,stream>>>(zacc, conv+OFF_WA+49152, conv+OFF_BA+384,
                                       conv+OFF_WB+49152, conv+OFF_BB+384,
                                       d_out, ZIS+128, 256, (long)0, 128, mode);
}

// Round 4
// 674.039 us; speedup vs baseline: 1.5593x; 1.5593x over previous
//
#include <hip/hip_runtime.h>
#include <stdint.h>

#define NNODES 20000
#define NEDGES 400000
#define MTILES 1250   // 20000/16

typedef __attribute__((ext_vector_type(8))) short short8;
typedef __attribute__((ext_vector_type(4))) float floatx4;

__device__ __forceinline__ float bf2f(uint16_t u){ return __uint_as_float(((uint32_t)u)<<16); }
__device__ __forceinline__ uint16_t f2bf(float f){
  uint32_t x = __float_as_uint(f);
  x += 0x7FFFu + ((x>>16)&1u);
  return (uint16_t)(x>>16);
}
__device__ __forceinline__ uint32_t packbf(float a, float b){
  return (uint32_t)f2bf(a) | ((uint32_t)f2bf(b)<<16);
}
__device__ __forceinline__ float2 bfpair(uint32_t v){
  return make_float2(__uint_as_float(v<<16), __uint_as_float(v & 0xFFFF0000u));
}
__device__ __forceinline__ float siluf(float x){ return x/(1.0f+__expf(-x)); }
__device__ __forceinline__ float ldf(const void* p, int i, int md){
  return (md==1) ? bf2f(((const uint16_t*)p)[i]) : ((const float*)p)[i];
}

// converted-weights layout (float elements within conv buffer)
#define OFF_V0   0
#define N_V0     32768
#define OFF_WS1  32768
#define N_WS1    16384
#define OFF_BS1  49152
#define N_BS1    128
#define OFF_V1   49280
#define N_V1     262144
#define OFF_WA   311424
#define N_WA     98304
#define OFF_BA   409728
#define N_BA     768
#define OFF_WB   410496
#define N_WB     98304
#define OFF_BB   508800
#define N_BB     768
#define N_CONV   509568

// ---------------- dtype probe ----------------
__global__ void k_probe(const void* dist, int* mode){
  if(threadIdx.x != 0 || blockIdx.x != 0) return;
  const float* f = (const float*)dist;
  const uint16_t* h = (const uint16_t*)dist;
  int okf = 1, okb = 1;
  for(int i=0;i<256;i++){
    float a = f[i];       okf &= (a >= 0.7f) & (a <= 5.1f);
    float b = bf2f(h[i]); okb &= (b >= 0.7f) & (b <= 5.1f);
  }
  *mode = okb ? 1 : (okf ? 0 : 1);
}

// ---------------- convert all weight tensors to fp32 ----------------
__global__ __launch_bounds__(256) void k_conv(const void* s0,const void* s1,const void* s2,const void* s3,
                                              const void* s4,const void* s5,const void* s6,const void* s7,
                                              const int* __restrict__ modep, float* __restrict__ dst){
  int md = *modep;
  int i = blockIdx.x*256 + threadIdx.x;
  if(i >= N_CONV) return;
  const void* src; int t = i;
  if(t < N_V0){src=s0;}
  else if((t-=N_V0) < N_WS1){src=s1;}
  else if((t-=N_WS1) < N_BS1){src=s2;}
  else if((t-=N_BS1) < N_V1){src=s3;}
  else if((t-=N_V1) < N_WA){src=s4;}
  else if((t-=N_WA) < N_BA){src=s5;}
  else if((t-=N_BA) < N_WB){src=s6;}
  else {t-=N_WB; src=s7;}
  dst[i] = ldf(src, t, md);
}

// ---------------- CSR build ----------------
__global__ __launch_bounds__(256) void k_hist(const int* __restrict__ src, int* __restrict__ cnt){
  int e = blockIdx.x*256 + threadIdx.x;
  if(e < NEDGES){
    int s = src[e];
    if((unsigned)s < NNODES) atomicAdd(&cnt[s], 1);
  }
}

__global__ __launch_bounds__(64) void k_scan(int* cnt_cur, int* offs){
  int t = threadIdx.x;
  const int chunk = (NNODES + 63)/64;   // 313
  int lo = t*chunk, hi = lo+chunk;
  if(lo > NNODES) lo = NNODES;
  if(hi > NNODES) hi = NNODES;
  int s = 0;
  for(int i=lo;i<hi;i++) s += cnt_cur[i];
  int v = s;
  #pragma unroll
  for(int d=1; d<64; d<<=1){
    int u = __shfl_up(v, d);
    if(t >= d) v += u;
  }
  int run = v - s;
  for(int i=lo;i<hi;i++){
    int c = cnt_cur[i];
    offs[i] = run;
    cnt_cur[i] = run;
    run += c;
  }
  if(t==63) offs[NNODES] = run;
}

// fill sorted edge arrays: dsts (dest node), sps (dest species), pos (e->slot)
__global__ __launch_bounds__(256) void k_fill(const int* __restrict__ src,
                                              const int* __restrict__ edst,
                                              const int* __restrict__ species,
                                              int* __restrict__ cur,
                                              int* __restrict__ dsts,
                                              int* __restrict__ sps,
                                              int* __restrict__ pos){
  int e = blockIdx.x*256 + threadIdx.x;
  if(e >= NEDGES) return;
  int s = src[e];
  if((unsigned)s >= NNODES) s = 0;
  int p = atomicAdd(&cur[s], 1);
  if((unsigned)p >= NEDGES) p = 0;
  pos[e] = p;
  int dn = edst[e];
  if((unsigned)dn >= NNODES) dn = 0;
  dsts[p] = dn;
  int sp = species[dn];
  if((unsigned)sp >= 51) sp = 0;
  sps[p] = sp;
}

// ---------------- radial basis -> sorted bf16 rows g_s[p][16] ----------------
__global__ __launch_bounds__(256) void k_G(const void* __restrict__ dist,
                                           const void* __restrict__ sw,
                                           const int* __restrict__ modep,
                                           const int* __restrict__ pos,
                                           uint16_t* __restrict__ gs){
  int e = blockIdx.x*256 + threadIdx.x;
  if(e >= NEDGES) return;
  int md = *modep;
  float r = ldf(dist, e, md);
  float w = ldf(sw, e, md);
  float rinv = 1.0f/r;
  const float sigma = 0.8f/15.0f;
  const float isig  = 15.0f/0.8f;
  uint32_t u[8];
  #pragma unroll
  for(int j=0;j<8;j++){
    float mu0 = 0.2f + sigma*(float)(2*j);
    float mu1 = 0.2f + sigma*(float)(2*j+1);
    float t0 = (rinv-mu0)*isig, t1 = (rinv-mu1)*isig;
    u[j] = packbf(w*__expf(-0.5f*t0*t0), w*__expf(-0.5f*t1*t1));
  }
  int p = pos[e];
  uint4* o = (uint4*)(gs + (size_t)p*16);
  o[0] = make_uint4(u[0],u[1],u[2],u[3]);
  o[1] = make_uint4(u[4],u[5],u[6],u[7]);
}

// ---------------- species tables: ZWs0[s][128] fp32, zfb[s][16] bf16 ----------------
__global__ __launch_bounds__(128) void k_spec(const void* __restrict__ Z,
                                              const void* __restrict__ Ws0,
                                              const void* __restrict__ bs0,
                                              const int* __restrict__ modep,
                                              float* __restrict__ ZWs0,
                                              uint16_t* __restrict__ zfb){
  int s = blockIdx.x, d = threadIdx.x;
  int md = *modep;
  float zk[16];
  #pragma unroll
  for(int k=0;k<16;k++) zk[k] = ldf(Z, s*16+k, md);
  float a = ldf(bs0, d, md);
  #pragma unroll
  for(int k=0;k<16;k++) a = fmaf(zk[k], ldf(Ws0, k*128+d, md), a);
  ZWs0[s*128+d] = a;
  if(d < 16) zfb[s*16+d] = f2bf(zk[d]);
}

// ---------------- pack V (Kx128 fp32) into MFMA B-fragment layout, bf16 ----------------
// frag elem: out[((kk*8+nt)*64+l)*8+j] = V[(kk*32+(l>>4)*8+j)*128 + nt*16+(l&15)]
__global__ __launch_bounds__(256) void k_prepB(const float* __restrict__ W, int Ksteps,
                                               uint16_t* __restrict__ Bf){
  int idx = blockIdx.x*256 + threadIdx.x;
  int total = Ksteps*8*64;
  if(idx >= total) return;
  int l = idx & 63, nt = (idx>>6)&7, kk = idx>>9;
  int kbase = kk*32 + (l>>4)*8;
  int dim = nt*16 + (l&15);
  uint32_t u[4];
  #pragma unroll
  for(int t=0;t<4;t++){
    float f0 = W[(size_t)(kbase+2*t)*128 + dim];
    float f1 = W[(size_t)(kbase+2*t+1)*128 + dim];
    u[t] = packbf(f0,f1);
  }
  ((uint4*)Bf)[idx] = make_uint4(u[0],u[1],u[2],u[3]);
}

// ---------------- layer-0 scatter: T0[n][b*16+zk] in A-frag layout (Ksteps=8) ----------------
__global__ __launch_bounds__(256) void k_scat0(const int* __restrict__ offs,
                                               const int* __restrict__ sps,
                                               const uint16_t* __restrict__ gs,
                                               const uint16_t* __restrict__ zfb,
                                               uint16_t* __restrict__ Tf){
  int w = threadIdx.x>>6, l = threadIdx.x&63;
  int n = blockIdx.x*4 + w;
  int u = l&31, dup = l>>5;
  int b = u>>1, zk0 = (u&1)*8;
  float acc[8];
  #pragma unroll
  for(int j=0;j<8;j++) acc[j]=0.f;
  int beg = offs[n], end = offs[n+1];
  for(int ei=beg+dup; ei<end; ei+=2){
    int sp = sps[ei];
    float g = bf2f(gs[(size_t)ei*16 + b]);
    uint4 z = *(const uint4*)(zfb + sp*16 + zk0);
    float2 f0=bfpair(z.x), f1=bfpair(z.y), f2=bfpair(z.z), f3=bfpair(z.w);
    acc[0]=fmaf(g,f0.x,acc[0]); acc[1]=fmaf(g,f0.y,acc[1]);
    acc[2]=fmaf(g,f1.x,acc[2]); acc[3]=fmaf(g,f1.y,acc[3]);
    acc[4]=fmaf(g,f2.x,acc[4]); acc[5]=fmaf(g,f2.y,acc[5]);
    acc[6]=fmaf(g,f3.x,acc[6]); acc[7]=fmaf(g,f3.y,acc[7]);
  }
  #pragma unroll
  for(int j=0;j<8;j++) acc[j] += __shfl(acc[j], l^32);
  if(dup==0){
    uint32_t p0 = packbf(acc[0],acc[1]), p1 = packbf(acc[2],acc[3]);
    uint32_t p2 = packbf(acc[4],acc[5]), p3 = packbf(acc[6],acc[7]);
    int kk = u>>2, q = u&3;
    size_t off = (((size_t)(n>>4)*8 + kk)*64 + q*16 + (n&15))*8;
    *(uint4*)(Tf + off) = make_uint4(p0,p1,p2,p3);
  }
}

// ---------------- layer-1 scatter: T[n][b*128+kz] in A-frag layout (Ksteps=64) ----------------
__global__ __launch_bounds__(256) void k_scat1(const int* __restrict__ offs,
                                               const int* __restrict__ dsts,
                                               const uint16_t* __restrict__ gs,
                                               const uint16_t* __restrict__ zib,
                                               uint16_t* __restrict__ Tf){
  int w = threadIdx.x>>6, l = threadIdx.x&63;
  int n = blockIdx.x*4 + w;
  int b = l&15, ks = l>>4;
  float acc[32];
  #pragma unroll
  for(int i=0;i<32;i++) acc[i]=0.f;
  int beg = offs[n], end = offs[n+1];
  int ei = beg;
  for(; ei+2<=end; ei+=2){
    int dn0 = dsts[ei], dn1 = dsts[ei+1];
    float g0 = bf2f(gs[(size_t)ei*16 + b]);
    float g1 = bf2f(gs[(size_t)(ei+1)*16 + b]);
    const uint4* z0p = (const uint4*)(zib + (size_t)dn0*128 + ks*32);
    const uint4* z1p = (const uint4*)(zib + (size_t)dn1*128 + ks*32);
    uint4 z0[4] = {z0p[0], z0p[1], z0p[2], z0p[3]};
    uint4 z1[4] = {z1p[0], z1p[1], z1p[2], z1p[3]};
    #pragma unroll
    for(int q=0;q<4;q++){
      float2 a0=bfpair(z0[q].x), a1=bfpair(z0[q].y), a2=bfpair(z0[q].z), a3=bfpair(z0[q].w);
      acc[q*8+0]=fmaf(g0,a0.x,acc[q*8+0]); acc[q*8+1]=fmaf(g0,a0.y,acc[q*8+1]);
      acc[q*8+2]=fmaf(g0,a1.x,acc[q*8+2]); acc[q*8+3]=fmaf(g0,a1.y,acc[q*8+3]);
      acc[q*8+4]=fmaf(g0,a2.x,acc[q*8+4]); acc[q*8+5]=fmaf(g0,a2.y,acc[q*8+5]);
      acc[q*8+6]=fmaf(g0,a3.x,acc[q*8+6]); acc[q*8+7]=fmaf(g0,a3.y,acc[q*8+7]);
      float2 b0=bfpair(z1[q].x), b1=bfpair(z1[q].y), b2=bfpair(z1[q].z), b3=bfpair(z1[q].w);
      acc[q*8+0]=fmaf(g1,b0.x,acc[q*8+0]); acc[q*8+1]=fmaf(g1,b0.y,acc[q*8+1]);
      acc[q*8+2]=fmaf(g1,b1.x,acc[q*8+2]); acc[q*8+3]=fmaf(g1,b1.y,acc[q*8+3]);
      acc[q*8+4]=fmaf(g1,b2.x,acc[q*8+4]); acc[q*8+5]=fmaf(g1,b2.y,acc[q*8+5]);
      acc[q*8+6]=fmaf(g1,b3.x,acc[q*8+6]); acc[q*8+7]=fmaf(g1,b3.y,acc[q*8+7]);
    }
  }
  if(ei < end){
    int dn0 = dsts[ei];
    float g0 = bf2f(gs[(size_t)ei*16 + b]);
    const uint4* z0p = (const uint4*)(zib + (size_t)dn0*128 + ks*32);
    #pragma unroll
    for(int q=0;q<4;q++){
      uint4 z = z0p[q];
      float2 a0=bfpair(z.x), a1=bfpair(z.y), a2=bfpair(z.z), a3=bfpair(z.w);
      acc[q*8+0]=fmaf(g0,a0.x,acc[q*8+0]); acc[q*8+1]=fmaf(g0,a0.y,acc[q*8+1]);
      acc[q*8+2]=fmaf(g0,a1.x,acc[q*8+2]); acc[q*8+3]=fmaf(g0,a1.y,acc[q*8+3]);
      acc[q*8+4]=fmaf(g0,a2.x,acc[q*8+4]); acc[q*8+5]=fmaf(g0,a2.y,acc[q*8+5]);
      acc[q*8+6]=fmaf(g0,a3.x,acc[q*8+6]); acc[q*8+7]=fmaf(g0,a3.y,acc[q*8+7]);
    }
  }
  int kk = b*4 + ks;
  size_t base = (((size_t)(n>>4)*64 + kk)*64 + (n&15))*8;
  #pragma unroll
  for(int g4=0; g4<4; g4++){
    uint32_t p0 = packbf(acc[g4*8+0],acc[g4*8+1]);
    uint32_t p1 = packbf(acc[g4*8+2],acc[g4*8+3]);
    uint32_t p2 = packbf(acc[g4*8+4],acc[g4*8+5]);
    uint32_t p3 = packbf(acc[g4*8+6],acc[g4*8+7]);
    *(uint4*)(Tf + base + (size_t)g4*16*8) = make_uint4(p0,p1,p2,p3);
  }
}

// ---------------- MFMA GEMM: out[n][d] = silu( (T@V)[n][d] + pre ) ----------------
// wave: gw = blk*4+w; mtile=gw>>1; nhalf=gw&1 (4 n-tiles each)
__global__ __launch_bounds__(256) void k_gemm(const uint16_t* __restrict__ Tf,
                                              const uint16_t* __restrict__ Bf,
                                              int Ksteps,
                                              const float* __restrict__ pre,
                                              const int* __restrict__ species,
                                              const float* __restrict__ ZWs0,
                                              float* __restrict__ out){
  int w = threadIdx.x>>6, l = threadIdx.x&63;
  int gw = blockIdx.x*4 + w;
  int mtile = gw>>1, nh = gw&1;
  if(mtile >= MTILES) return;
  floatx4 acc[4];
  #pragma unroll
  for(int t=0;t<4;t++) acc[t] = (floatx4){0.f,0.f,0.f,0.f};
  const short8* Ap = (const short8*)Tf + (size_t)mtile*Ksteps*64 + l;
  const short8* Bp = (const short8*)Bf + (size_t)(nh*4)*64 + l;
  for(int kk=0; kk<Ksteps; kk++){
    short8 a = Ap[(size_t)kk*64];
    #pragma unroll
    for(int t=0;t<4;t++){
      short8 bb = Bp[(size_t)(kk*8+t)*64];
      acc[t] = __builtin_amdgcn_mfma_f32_16x16x32_bf16(a, bb, acc[t], 0, 0, 0);
    }
  }
  int col = l&15, quad = l>>4;
  #pragma unroll
  for(int t=0;t<4;t++){
    #pragma unroll
    for(int reg=0;reg<4;reg++){
      int node = mtile*16 + quad*4 + reg;
      int dim  = (nh*4+t)*16 + col;
      float p;
      if(species){
        int sp = species[node];
        if((unsigned)sp >= 51) sp = 0;
        p = ZWs0[sp*128 + dim];
      } else {
        p = pre[(size_t)node*128 + dim];
      }
      out[(size_t)node*128 + dim] = siluf(acc[t][reg] + p);
    }
  }
}

// ---------------- zi fp32 -> bf16 copy ----------------
__global__ __launch_bounds__(256) void k_tobf(const float* __restrict__ zi, uint16_t* __restrict__ zib){
  int i = blockIdx.x*256 + threadIdx.x;
  if(i < NNODES*128) zib[i] = f2bf(zi[i]);
}

// ---------------- zself1 = zi @ Ws1 + bs1 ----------------
__global__ __launch_bounds__(256) void k_linear(const float* __restrict__ zi,
                                                const float* __restrict__ W,
                                                const float* __restrict__ bias,
                                                float* __restrict__ out){
  __shared__ float zT[4][512];
  int w = threadIdx.x>>6, lane = threadIdx.x&63;
  int n0 = blockIdx.x*16 + w*4;
  int d0 = lane*2;
  float* z = zT[w];
  #pragma unroll
  for(int i=0;i<8;i++){
    int idx = lane + 64*i; int ni = idx>>7; int k = idx&127;
    z[k*4+ni] = zi[(size_t)(n0+ni)*128 + k];
  }
  __syncthreads();
  float b0 = bias[d0], b1 = bias[d0+1];
  float2 acc[4];
  #pragma unroll
  for(int ni=0;ni<4;ni++) acc[ni] = make_float2(b0,b1);
  #pragma unroll 8
  for(int k=0;k<128;k++){
    float4 z4 = *(const float4*)(z + k*4);
    float2 wv = *(const float2*)(&W[(size_t)k*128 + d0]);
    acc[0].x = fmaf(z4.x, wv.x, acc[0].x); acc[0].y = fmaf(z4.x, wv.y, acc[0].y);
    acc[1].x = fmaf(z4.y, wv.x, acc[1].x); acc[1].y = fmaf(z4.y, wv.y, acc[1].y);
    acc[2].x = fmaf(z4.z, wv.x, acc[2].x); acc[2].y = fmaf(z4.z, wv.y, acc[2].y);
    acc[3].x = fmaf(z4.w, wv.x, acc[3].x); acc[3].y = fmaf(z4.w, wv.y, acc[3].y);
  }
  #pragma unroll
  for(int ni=0;ni<4;ni++)
    *(float2*)(out + (size_t)(n0+ni)*128 + d0) = acc[ni];
}

// ---------------- onsite: 3 x (h=silu(z@Wa+ba); z+=h@Wb+bb) ----------------
__global__ __launch_bounds__(256) void k_onsite(float* __restrict__ zi,
                                                const float* __restrict__ Wa,
                                                const float* __restrict__ ba,
                                                const float* __restrict__ Wb,
                                                const float* __restrict__ bb,
                                                void* __restrict__ outb,
                                                long off1, int st1,
                                                long off2, int st2,
                                                const int* __restrict__ modep){
  __shared__ float zT[4][512];
  __shared__ float hT[4][512];
  int w = threadIdx.x>>6, lane = threadIdx.x&63;
  int n0 = blockIdx.x*16 + w*4;
  int d0 = lane*2;
  int md = *modep;
  float* z = zT[w];
  float* h = hT[w];
  #pragma unroll
  for(int i=0;i<8;i++){
    int idx = lane + 64*i; int ni = idx>>7; int k = idx&127;
    z[k*4+ni] = zi[(size_t)(n0+ni)*128 + k];
  }
  __syncthreads();
  for(int j=0;j<3;j++){
    const float* Wap = Wa + (size_t)j*16384;
    float a0 = ba[j*128+d0], a1 = ba[j*128+d0+1];
    float2 acc[4];
    #pragma unroll
    for(int ni=0;ni<4;ni++) acc[ni] = make_float2(a0,a1);
    #pragma unroll 8
    for(int k=0;k<128;k++){
      float4 z4 = *(const float4*)(z + k*4);
      float2 wv = *(const float2*)(&Wap[(size_t)k*128 + d0]);
      acc[0].x = fmaf(z4.x, wv.x, acc[0].x); acc[0].y = fmaf(z4.x, wv.y, acc[0].y);
      acc[1].x = fmaf(z4.y, wv.x, acc[1].x); acc[1].y = fmaf(z4.y, wv.y, acc[1].y);
      acc[2].x = fmaf(z4.z, wv.x, acc[2].x); acc[2].y = fmaf(z4.z, wv.y, acc[2].y);
      acc[3].x = fmaf(z4.w, wv.x, acc[3].x); acc[3].y = fmaf(z4.w, wv.y, acc[3].y);
    }
    __syncthreads();
    *(float4*)(h + d0*4)     = make_float4(siluf(acc[0].x), siluf(acc[1].x), siluf(acc[2].x), siluf(acc[3].x));
    *(float4*)(h + (d0+1)*4) = make_float4(siluf(acc[0].y), siluf(acc[1].y), siluf(acc[2].y), siluf(acc[3].y));
    __syncthreads();
    const float* Wbp = Wb + (size_t)j*16384;
    float c0 = bb[j*128+d0], c1 = bb[j*128+d0+1];
    float2 r[4];
    #pragma unroll
    for(int ni=0;ni<4;ni++)
      r[ni] = make_float2(z[d0*4+ni] + c0, z[(d0+1)*4+ni] + c1);
    #pragma unroll 8
    for(int k=0;k<128;k++){
      float4 h4 = *(const float4*)(h + k*4);
      float2 wv = *(const float2*)(&Wbp[(size_t)k*128 + d0]);
      r[0].x = fmaf(h4.x, wv.x, r[0].x); r[0].y = fmaf(h4.x, wv.y, r[0].y);
      r[1].x = fmaf(h4.y, wv.x, r[1].x); r[1].y = fmaf(h4.y, wv.y, r[1].y);
      r[2].x = fmaf(h4.z, wv.x, r[2].x); r[2].y = fmaf(h4.z, wv.y, r[2].y);
      r[3].x = fmaf(h4.w, wv.x, r[3].x); r[3].y = fmaf(h4.w, wv.y, r[3].y);
    }
    __syncthreads();
    *(float4*)(z + d0*4)     = make_float4(r[0].x, r[1].x, r[2].x, r[3].x);
    *(float4*)(z + (d0+1)*4) = make_float4(r[0].y, r[1].y, r[2].y, r[3].y);
    __syncthreads();
  }
  #pragma unroll
  for(int i=0;i<8;i++){
    int idx = lane + 64*i; int ni = idx>>7; int k = idx&127;
    int n = n0 + ni;
    float v = z[k*4+ni];
    zi[(size_t)n*128 + k] = v;
    if(md==1){
      uint16_t* ob = (uint16_t*)outb;
      uint16_t hb = f2bf(v);
      ob[off1 + (long)n*st1 + k] = hb;
      if(off2 >= 0) ob[off2 + (long)n*st2 + k] = hb;
    } else {
      float* ob = (float*)outb;
      ob[off1 + (long)n*st1 + k] = v;
      if(off2 >= 0) ob[off2 + (long)n*st2 + k] = v;
    }
  }
}

extern "C" void kernel_launch(void* const* d_in, const int* in_sizes, int n_in,
                              void* d_out, int out_size, void* d_ws, size_t ws_size,
                              hipStream_t stream){
  const int* species = (const int*)d_in[0];
  const int* esrc    = (const int*)d_in[1];
  const int* edst    = (const int*)d_in[2];
  const void* dist   = d_in[3];
  const void* swit   = d_in[4];
  const void* Z      = d_in[5];
  const void* Ws0    = d_in[6];
  const void* bs0    = d_in[7];
  const void* V0     = d_in[8];
  const void* Ws1    = d_in[9];
  const void* bs1    = d_in[10];
  const void* V1     = d_in[11];
  const void* Wa     = d_in[12];
  const void* ba     = d_in[13];
  const void* Wb     = d_in[14];
  const void* bb     = d_in[15];

  char* ws = (char*)d_ws;
  size_t off = 0;
  auto alloc = [&](size_t bytes)->void*{ void* p = ws + off; off = (off + bytes + 255) & ~(size_t)255; return p; };
  int*      offs = (int*)     alloc((size_t)(NNODES+1)*4);
  int*      cur  = (int*)     alloc((size_t)NNODES*4);
  int*      pos  = (int*)     alloc((size_t)NEDGES*4);
  int*      dsts = (int*)     alloc((size_t)NEDGES*4);
  int*      sps  = (int*)     alloc((size_t)NEDGES*4);
  uint16_t* gs   = (uint16_t*)alloc((size_t)NEDGES*16*2);    // 12.8 MB
  float*    zi   = (float*)   alloc((size_t)NNODES*128*4);   // 10.24 MB
  float*    zacc = (float*)   alloc((size_t)NNODES*128*4);   // 10.24 MB
  uint16_t* zib  = (uint16_t*)alloc((size_t)NNODES*128*2);   // 5.12 MB
  float*    ZWs0 = (float*)   alloc((size_t)51*128*4);
  uint16_t* zfb  = (uint16_t*)alloc((size_t)51*16*2);
  float*    conv = (float*)   alloc((size_t)N_CONV*4);       // 2.04 MB
  uint16_t* Bf0  = (uint16_t*)alloc((size_t)8*8*64*8*2);     // 64 KB
  uint16_t* Bf1  = (uint16_t*)alloc((size_t)64*8*64*8*2);    // 512 KB
  int*      mode = (int*)     alloc(256);
  uint16_t* Tf   = (uint16_t*)alloc((size_t)MTILES*64*64*8*2); // 81.92 MB (last: largest)

  const int EB = (NEDGES+255)/256;
  hipMemsetAsync(cur, 0, NNODES*4, stream);
  k_probe<<<1,64,0,stream>>>(dist, mode);
  k_conv <<<(N_CONV+255)/256,256,0,stream>>>(V0, Ws1, bs1, V1, Wa, ba, Wb, bb, mode, conv);
  k_hist <<<EB,256,0,stream>>>(esrc, cur);
  k_scan <<<1,64,0,stream>>>(cur, offs);
  k_fill <<<EB,256,0,stream>>>(esrc, edst, species, cur, dsts, sps, pos);
  k_G    <<<EB,256,0,stream>>>(dist, swit, mode, pos, gs);
  k_spec <<<51,128,0,stream>>>(Z, Ws0, bs0, mode, ZWs0, zfb);
  k_prepB<<<(8*8*64+255)/256,256,0,stream>>>(conv+OFF_V0, 8,  Bf0);
  k_prepB<<<(64*8*64+255)/256,256,0,stream>>>(conv+OFF_V1, 64, Bf1);

  const long ZIS = (long)NNODES*128;

  // layer 0
  k_scat0<<<NNODES/4,256,0,stream>>>(offs, sps, gs, zfb, Tf);
  k_gemm <<<(MTILES*2+3)/4,256,0,stream>>>(Tf, Bf0, 8, (const float*)nullptr, species, ZWs0, zi);
  k_onsite<<<NNODES/16,256,0,stream>>>(zi, conv+OFF_WA, conv+OFF_BA, conv+OFF_WB, conv+OFF_BB,
                                       d_out, ZIS, 256, (long)-1, 0, mode);

  // layer 1
  k_tobf  <<<(NNODES*128+255)/256,256,0,stream>>>(zi, zib);
  k_linear<<<NNODES/16,256,0,stream>>>(zi, conv+OFF_WS1, conv+OFF_BS1, zacc);
  k_scat1 <<<NNODES/4,256,0,stream>>>(offs, dsts, gs, zib, Tf);
  k_gemm  <<<(MTILES*2+3)/4,256,0,stream>>>(Tf, Bf1, 64, zacc, (const int*)nullptr, (const float*)nullptr, zi);
  k_onsite<<<NNODES/16,256,0,stream>>>(zi, conv+OFF_WA+49152, conv+OFF_BA+384,
                                       conv+OFF_WB+49152, conv+OFF_BB+384,
                                       d_out, ZIS+128, 256, (long)0, 128, mode);
}

// Round 5
// 555.460 us; speedup vs baseline: 1.8922x; 1.2135x over previous
//
#include <hip/hip_runtime.h>
#include <stdint.h>

#define NNODES 20000
#define NEDGES 400000
#define MTILES 1250   // 20000/16
#define KS1 68        // layer-1 msg GEMM ksteps: 64 (T@V1) + 4 (zi@Ws1)

typedef __attribute__((ext_vector_type(8))) short short8;
typedef __attribute__((ext_vector_type(4))) float floatx4;

__device__ __forceinline__ float bf2f(uint16_t u){ return __uint_as_float(((uint32_t)u)<<16); }
__device__ __forceinline__ uint16_t f2bf(float f){
  uint32_t x = __float_as_uint(f);
  x += 0x7FFFu + ((x>>16)&1u);
  return (uint16_t)(x>>16);
}
__device__ __forceinline__ uint32_t packbf(float a, float b){
  return (uint32_t)f2bf(a) | ((uint32_t)f2bf(b)<<16);
}
__device__ __forceinline__ float2 bfpair(uint32_t v){
  return make_float2(__uint_as_float(v<<16), __uint_as_float(v & 0xFFFF0000u));
}
__device__ __forceinline__ float siluf(float x){ return x/(1.0f+__expf(-x)); }
__device__ __forceinline__ float ldf(const void* p, int i, int md){
  return (md==1) ? bf2f(((const uint16_t*)p)[i]) : ((const float*)p)[i];
}

// converted-weights layout (float elements within conv buffer)
#define OFF_V0   0
#define N_V0     32768
#define OFF_WS1  32768
#define N_WS1    16384
#define OFF_BS1  49152
#define N_BS1    128
#define OFF_V1   49280
#define N_V1     262144
#define OFF_WA   311424
#define N_WA     98304
#define OFF_BA   409728
#define N_BA     768
#define OFF_WB   410496
#define N_WB     98304
#define OFF_BB   508800
#define N_BB     768
#define N_CONV   509568

// ---------------- dtype probe ----------------
__global__ void k_probe(const void* dist, int* mode){
  if(threadIdx.x != 0 || blockIdx.x != 0) return;
  const float* f = (const float*)dist;
  const uint16_t* h = (const uint16_t*)dist;
  int okf = 1, okb = 1;
  for(int i=0;i<256;i++){
    float a = f[i];       okf &= (a >= 0.7f) & (a <= 5.1f);
    float b = bf2f(h[i]); okb &= (b >= 0.7f) & (b <= 5.1f);
  }
  *mode = okb ? 1 : (okf ? 0 : 1);
}

// ---------------- convert all weight tensors to fp32 ----------------
__global__ __launch_bounds__(256) void k_conv(const void* s0,const void* s1,const void* s2,const void* s3,
                                              const void* s4,const void* s5,const void* s6,const void* s7,
                                              const int* __restrict__ modep, float* __restrict__ dst){
  int md = *modep;
  int i = blockIdx.x*256 + threadIdx.x;
  if(i >= N_CONV) return;
  const void* src; int t = i;
  if(t < N_V0){src=s0;}
  else if((t-=N_V0) < N_WS1){src=s1;}
  else if((t-=N_WS1) < N_BS1){src=s2;}
  else if((t-=N_BS1) < N_V1){src=s3;}
  else if((t-=N_V1) < N_WA){src=s4;}
  else if((t-=N_WA) < N_BA){src=s5;}
  else if((t-=N_BA) < N_WB){src=s6;}
  else {t-=N_WB; src=s7;}
  dst[i] = ldf(src, t, md);
}

// ---------------- CSR build ----------------
__global__ __launch_bounds__(256) void k_hist(const int* __restrict__ src, int* __restrict__ cnt){
  int e = blockIdx.x*256 + threadIdx.x;
  if(e < NEDGES){
    int s = src[e];
    if((unsigned)s < NNODES) atomicAdd(&cnt[s], 1);
  }
}

__global__ __launch_bounds__(64) void k_scan(int* cnt_cur, int* offs){
  int t = threadIdx.x;
  const int chunk = (NNODES + 63)/64;   // 313
  int lo = t*chunk, hi = lo+chunk;
  if(lo > NNODES) lo = NNODES;
  if(hi > NNODES) hi = NNODES;
  int s = 0;
  for(int i=lo;i<hi;i++) s += cnt_cur[i];
  int v = s;
  #pragma unroll
  for(int d=1; d<64; d<<=1){
    int u = __shfl_up(v, d);
    if(t >= d) v += u;
  }
  int run = v - s;
  for(int i=lo;i<hi;i++){
    int c = cnt_cur[i];
    offs[i] = run;
    cnt_cur[i] = run;
    run += c;
  }
  if(t==63) offs[NNODES] = run;
}

__global__ __launch_bounds__(256) void k_fill(const int* __restrict__ src,
                                              const int* __restrict__ edst,
                                              const int* __restrict__ species,
                                              int* __restrict__ cur,
                                              int* __restrict__ dsts,
                                              int* __restrict__ sps,
                                              int* __restrict__ pos){
  int e = blockIdx.x*256 + threadIdx.x;
  if(e >= NEDGES) return;
  int s = src[e];
  if((unsigned)s >= NNODES) s = 0;
  int p = atomicAdd(&cur[s], 1);
  if((unsigned)p >= NEDGES) p = 0;
  pos[e] = p;
  int dn = edst[e];
  if((unsigned)dn >= NNODES) dn = 0;
  dsts[p] = dn;
  int sp = species[dn];
  if((unsigned)sp >= 51) sp = 0;
  sps[p] = sp;
}

// ---------------- radial basis -> sorted bf16 rows g_s[p][16] ----------------
__global__ __launch_bounds__(256) void k_G(const void* __restrict__ dist,
                                           const void* __restrict__ sw,
                                           const int* __restrict__ modep,
                                           const int* __restrict__ pos,
                                           uint16_t* __restrict__ gs){
  int e = blockIdx.x*256 + threadIdx.x;
  if(e >= NEDGES) return;
  int md = *modep;
  float r = ldf(dist, e, md);
  float w = ldf(sw, e, md);
  float rinv = 1.0f/r;
  const float sigma = 0.8f/15.0f;
  const float isig  = 15.0f/0.8f;
  uint32_t u[8];
  #pragma unroll
  for(int j=0;j<8;j++){
    float mu0 = 0.2f + sigma*(float)(2*j);
    float mu1 = 0.2f + sigma*(float)(2*j+1);
    float t0 = (rinv-mu0)*isig, t1 = (rinv-mu1)*isig;
    u[j] = packbf(w*__expf(-0.5f*t0*t0), w*__expf(-0.5f*t1*t1));
  }
  int p = pos[e];
  uint4* o = (uint4*)(gs + (size_t)p*16);
  o[0] = make_uint4(u[0],u[1],u[2],u[3]);
  o[1] = make_uint4(u[4],u[5],u[6],u[7]);
}

// ---------------- species tables ----------------
__global__ __launch_bounds__(128) void k_spec(const void* __restrict__ Z,
                                              const void* __restrict__ Ws0,
                                              const void* __restrict__ bs0,
                                              const int* __restrict__ modep,
                                              float* __restrict__ ZWs0,
                                              uint16_t* __restrict__ zfb){
  int s = blockIdx.x, d = threadIdx.x;
  int md = *modep;
  float zk[16];
  #pragma unroll
  for(int k=0;k<16;k++) zk[k] = ldf(Z, s*16+k, md);
  float a = ldf(bs0, d, md);
  #pragma unroll
  for(int k=0;k<16;k++) a = fmaf(zk[k], ldf(Ws0, k*128+d, md), a);
  ZWs0[s*128+d] = a;
  if(d < 16) zfb[s*16+d] = f2bf(zk[d]);
}

// ---------------- pack W (Kx128 fp32) into MFMA B-fragment layout, bf16 ----------------
// out[((kk*8+nt)*64+l)*8+j] = W[(kk*32+(l>>4)*8+j)*128 + nt*16+(l&15)]
__global__ __launch_bounds__(256) void k_prepB(const float* __restrict__ W, int Ksteps,
                                               uint16_t* __restrict__ Bf){
  int idx = blockIdx.x*256 + threadIdx.x;
  int total = Ksteps*8*64;
  if(idx >= total) return;
  int l = idx & 63, nt = (idx>>6)&7, kk = idx>>9;
  int kbase = kk*32 + (l>>4)*8;
  int dim = nt*16 + (l&15);
  uint32_t u[4];
  #pragma unroll
  for(int t=0;t<4;t++){
    float f0 = W[(size_t)(kbase+2*t)*128 + dim];
    float f1 = W[(size_t)(kbase+2*t+1)*128 + dim];
    u[t] = packbf(f0,f1);
  }
  ((uint4*)Bf)[idx] = make_uint4(u[0],u[1],u[2],u[3]);
}

// pack all 12 onsite 128x128 weights (Wa L0 j0..2, Wa L1 j0..2, Wb L0, Wb L1) into frags
__global__ __launch_bounds__(256) void k_prepW(const float* __restrict__ conv,
                                               uint16_t* __restrict__ Wf){
  int idx = blockIdx.x*256 + threadIdx.x;
  if(idx >= 12*2048) return;
  int wi = idx>>11, r = idx&2047;
  int l = r & 63, nt = (r>>6)&7, kk = r>>9;
  const float* W = conv + ((wi<6) ? (OFF_WA + wi*16384) : (OFF_WB + (wi-6)*16384));
  int kbase = kk*32 + (l>>4)*8;
  int dim = nt*16 + (l&15);
  uint32_t u[4];
  #pragma unroll
  for(int t=0;t<4;t++){
    float f0 = W[(size_t)(kbase+2*t)*128 + dim];
    float f1 = W[(size_t)(kbase+2*t+1)*128 + dim];
    u[t] = packbf(f0,f1);
  }
  ((uint4*)Wf)[idx] = make_uint4(u[0],u[1],u[2],u[3]);
}

// ---------------- layer-0 scatter: T0 A-frag (Ksteps=8) ----------------
__global__ __launch_bounds__(256) void k_scat0(const int* __restrict__ offs,
                                               const int* __restrict__ sps,
                                               const uint16_t* __restrict__ gs,
                                               const uint16_t* __restrict__ zfb,
                                               uint16_t* __restrict__ Tf){
  int w = threadIdx.x>>6, l = threadIdx.x&63;
  int n = blockIdx.x*4 + w;
  int u = l&31, dup = l>>5;
  int b = u>>1, zk0 = (u&1)*8;
  float acc[8];
  #pragma unroll
  for(int j=0;j<8;j++) acc[j]=0.f;
  int beg = offs[n], end = offs[n+1];
  for(int ei=beg+dup; ei<end; ei+=2){
    int sp = sps[ei];
    float g = bf2f(gs[(size_t)ei*16 + b]);
    uint4 z = *(const uint4*)(zfb + sp*16 + zk0);
    float2 f0=bfpair(z.x), f1=bfpair(z.y), f2=bfpair(z.z), f3=bfpair(z.w);
    acc[0]=fmaf(g,f0.x,acc[0]); acc[1]=fmaf(g,f0.y,acc[1]);
    acc[2]=fmaf(g,f1.x,acc[2]); acc[3]=fmaf(g,f1.y,acc[3]);
    acc[4]=fmaf(g,f2.x,acc[4]); acc[5]=fmaf(g,f2.y,acc[5]);
    acc[6]=fmaf(g,f3.x,acc[6]); acc[7]=fmaf(g,f3.y,acc[7]);
  }
  #pragma unroll
  for(int j=0;j<8;j++) acc[j] += __shfl(acc[j], l^32);
  if(dup==0){
    uint32_t p0 = packbf(acc[0],acc[1]), p1 = packbf(acc[2],acc[3]);
    uint32_t p2 = packbf(acc[4],acc[5]), p3 = packbf(acc[6],acc[7]);
    int kk = u>>2, q = u&3;
    size_t off = (((size_t)(n>>4)*8 + kk)*64 + q*16 + (n&15))*8;
    *(uint4*)(Tf + off) = make_uint4(p0,p1,p2,p3);
  }
}

// ---------------- layer-1 scatter: T A-frag ksteps 0..63 of KS1 ----------------
__global__ __launch_bounds__(256) void k_scat1(const int* __restrict__ offs,
                                               const int* __restrict__ dsts,
                                               const uint16_t* __restrict__ gs,
                                               const uint16_t* __restrict__ zib,
                                               uint16_t* __restrict__ Tf){
  int w = threadIdx.x>>6, l = threadIdx.x&63;
  int n = blockIdx.x*4 + w;
  int b = l&15, ks = l>>4;
  float acc[32];
  #pragma unroll
  for(int i=0;i<32;i++) acc[i]=0.f;
  int beg = offs[n], end = offs[n+1];
  int ei = beg;
  for(; ei+2<=end; ei+=2){
    int dn0 = dsts[ei], dn1 = dsts[ei+1];
    float g0 = bf2f(gs[(size_t)ei*16 + b]);
    float g1 = bf2f(gs[(size_t)(ei+1)*16 + b]);
    const uint4* z0p = (const uint4*)(zib + (size_t)dn0*128 + ks*32);
    const uint4* z1p = (const uint4*)(zib + (size_t)dn1*128 + ks*32);
    uint4 z0[4] = {z0p[0], z0p[1], z0p[2], z0p[3]};
    uint4 z1[4] = {z1p[0], z1p[1], z1p[2], z1p[3]};
    #pragma unroll
    for(int q=0;q<4;q++){
      float2 a0=bfpair(z0[q].x), a1=bfpair(z0[q].y), a2=bfpair(z0[q].z), a3=bfpair(z0[q].w);
      acc[q*8+0]=fmaf(g0,a0.x,acc[q*8+0]); acc[q*8+1]=fmaf(g0,a0.y,acc[q*8+1]);
      acc[q*8+2]=fmaf(g0,a1.x,acc[q*8+2]); acc[q*8+3]=fmaf(g0,a1.y,acc[q*8+3]);
      acc[q*8+4]=fmaf(g0,a2.x,acc[q*8+4]); acc[q*8+5]=fmaf(g0,a2.y,acc[q*8+5]);
      acc[q*8+6]=fmaf(g0,a3.x,acc[q*8+6]); acc[q*8+7]=fmaf(g0,a3.y,acc[q*8+7]);
      float2 b0=bfpair(z1[q].x), b1=bfpair(z1[q].y), b2=bfpair(z1[q].z), b3=bfpair(z1[q].w);
      acc[q*8+0]=fmaf(g1,b0.x,acc[q*8+0]); acc[q*8+1]=fmaf(g1,b0.y,acc[q*8+1]);
      acc[q*8+2]=fmaf(g1,b1.x,acc[q*8+2]); acc[q*8+3]=fmaf(g1,b1.y,acc[q*8+3]);
      acc[q*8+4]=fmaf(g1,b2.x,acc[q*8+4]); acc[q*8+5]=fmaf(g1,b2.y,acc[q*8+5]);
      acc[q*8+6]=fmaf(g1,b3.x,acc[q*8+6]); acc[q*8+7]=fmaf(g1,b3.y,acc[q*8+7]);
    }
  }
  if(ei < end){
    int dn0 = dsts[ei];
    float g0 = bf2f(gs[(size_t)ei*16 + b]);
    const uint4* z0p = (const uint4*)(zib + (size_t)dn0*128 + ks*32);
    #pragma unroll
    for(int q=0;q<4;q++){
      uint4 z = z0p[q];
      float2 a0=bfpair(z.x), a1=bfpair(z.y), a2=bfpair(z.z), a3=bfpair(z.w);
      acc[q*8+0]=fmaf(g0,a0.x,acc[q*8+0]); acc[q*8+1]=fmaf(g0,a0.y,acc[q*8+1]);
      acc[q*8+2]=fmaf(g0,a1.x,acc[q*8+2]); acc[q*8+3]=fmaf(g0,a1.y,acc[q*8+3]);
      acc[q*8+4]=fmaf(g0,a2.x,acc[q*8+4]); acc[q*8+5]=fmaf(g0,a2.y,acc[q*8+5]);
      acc[q*8+6]=fmaf(g0,a3.x,acc[q*8+6]); acc[q*8+7]=fmaf(g0,a3.y,acc[q*8+7]);
    }
  }
  int kk = b*4 + ks;
  size_t base = (((size_t)(n>>4)*KS1 + kk)*64 + (n&15))*8;
  #pragma unroll
  for(int g4=0; g4<4; g4++){
    uint32_t p0 = packbf(acc[g4*8+0],acc[g4*8+1]);
    uint32_t p1 = packbf(acc[g4*8+2],acc[g4*8+3]);
    uint32_t p2 = packbf(acc[g4*8+4],acc[g4*8+5]);
    uint32_t p3 = packbf(acc[g4*8+6],acc[g4*8+7]);
    *(uint4*)(Tf + base + (size_t)g4*16*8) = make_uint4(p0,p1,p2,p3);
  }
}

// ---------------- pack zi into zib (linear) + Tf A-frag ksteps 64..67 ----------------
__global__ __launch_bounds__(128) void k_packz(const float* __restrict__ zi,
                                               uint16_t* __restrict__ zib,
                                               uint16_t* __restrict__ Tf){
  int w = threadIdx.x>>6, l = threadIdx.x&63;
  int mtile = blockIdx.x*2 + w;
  int n0 = mtile*16;
  #pragma unroll
  for(int i=0;i<4;i++){
    int flat = i*512 + l*8;
    int node = flat>>7, k = flat&127;
    const float4* zp = (const float4*)(zi + (size_t)(n0+node)*128 + k);
    float4 a = zp[0], b = zp[1];
    uint4 o = make_uint4(packbf(a.x,a.y),packbf(a.z,a.w),packbf(b.x,b.y),packbf(b.z,b.w));
    *(uint4*)(zib + (size_t)(n0+node)*128 + k) = o;
  }
  int m = l&15, q = l>>4;
  #pragma unroll
  for(int kk=0;kk<4;kk++){
    const float4* zp = (const float4*)(zi + (size_t)(n0+m)*128 + kk*32 + q*8);
    float4 a = zp[0], b = zp[1];
    uint4 o = make_uint4(packbf(a.x,a.y),packbf(a.z,a.w),packbf(b.x,b.y),packbf(b.z,b.w));
    *(uint4*)(Tf + (((size_t)mtile*KS1 + 64 + kk)*64 + l)*8) = o;
  }
}

// ---------------- MFMA GEMM: out = silu(T@B + pre) ----------------
__global__ __launch_bounds__(256) void k_gemm(const uint16_t* __restrict__ Tf,
                                              const uint16_t* __restrict__ Bf,
                                              int Ksteps,
                                              const int* __restrict__ species,
                                              const float* __restrict__ ZWs0,
                                              const float* __restrict__ bias,
                                              float* __restrict__ out){
  int w = threadIdx.x>>6, l = threadIdx.x&63;
  int gw = blockIdx.x*4 + w;
  int mtile = gw>>1, nh = gw&1;
  if(mtile >= MTILES) return;
  floatx4 acc[4];
  #pragma unroll
  for(int t=0;t<4;t++) acc[t] = (floatx4){0.f,0.f,0.f,0.f};
  const short8* Ap = (const short8*)Tf + (size_t)mtile*Ksteps*64 + l;
  const short8* Bp = (const short8*)Bf + (size_t)(nh*4)*64 + l;
  for(int kk=0; kk<Ksteps; kk++){
    short8 a = Ap[(size_t)kk*64];
    #pragma unroll
    for(int t=0;t<4;t++){
      short8 bb = Bp[(size_t)(kk*8+t)*64];
      acc[t] = __builtin_amdgcn_mfma_f32_16x16x32_bf16(a, bb, acc[t], 0, 0, 0);
    }
  }
  int col = l&15, quad = l>>4;
  #pragma unroll
  for(int t=0;t<4;t++){
    #pragma unroll
    for(int reg=0;reg<4;reg++){
      int node = mtile*16 + quad*4 + reg;
      int dim  = (nh*4+t)*16 + col;
      float p;
      if(species){
        int sp = species[node];
        if((unsigned)sp >= 51) sp = 0;
        p = ZWs0[sp*128 + dim];
      } else {
        p = bias[dim];
      }
      out[(size_t)node*128 + dim] = siluf(acc[t][reg] + p);
    }
  }
}

// ---------------- onsite via MFMA: 3 x (h=silu(z@Wa+ba); z+=h@Wb+bb) ----------------
// 1 wave per 16-node tile; z/h in LDS fp32 stride 132 (pad kills conflicts)
__global__ __launch_bounds__(128) void k_onsite(float* __restrict__ zi,
                                                const uint16_t* __restrict__ Waf,
                                                const float* __restrict__ ba,
                                                const uint16_t* __restrict__ Wbf,
                                                const float* __restrict__ bb,
                                                void* __restrict__ outb,
                                                long off1, int st1,
                                                long off2, int st2,
                                                const int* __restrict__ modep){
  __shared__ float zbuf[2][16*132];
  __shared__ float hbuf[2][16*132];
  int w = threadIdx.x>>6, l = threadIdx.x&63;
  int mtile = blockIdx.x*2 + w;
  int n0 = mtile*16;
  int md = *modep;
  float* zb = zbuf[w];
  float* hb = hbuf[w];
  #pragma unroll
  for(int i=0;i<8;i++){
    int flat = (i*64 + l)*4;
    int node = flat>>7, k = flat&127;
    *(float4*)(zb + node*132 + k) = *(const float4*)(zi + (size_t)(n0+node)*128 + k);
  }
  __syncthreads();
  int m = l&15, q = l>>4;
  for(int j=0;j<3;j++){
    // GEMM1: h = silu(z@Wa + ba)
    const short8* Ba = (const short8*)Waf + (size_t)j*2048 + l;
    floatx4 acc[8];
    #pragma unroll
    for(int t=0;t<8;t++) acc[t] = (floatx4){0.f,0.f,0.f,0.f};
    #pragma unroll
    for(int kk=0;kk<4;kk++){
      const float* zp = zb + m*132 + kk*32 + q*8;
      float4 a0 = *(const float4*)zp, a1 = *(const float4*)(zp+4);
      union { short8 s; uint32_t u[4]; } A;
      A.u[0]=packbf(a0.x,a0.y); A.u[1]=packbf(a0.z,a0.w);
      A.u[2]=packbf(a1.x,a1.y); A.u[3]=packbf(a1.z,a1.w);
      #pragma unroll
      for(int nt=0;nt<8;nt++){
        short8 bfr = Ba[(size_t)(kk*8+nt)*64];
        acc[nt] = __builtin_amdgcn_mfma_f32_16x16x32_bf16(A.s, bfr, acc[nt], 0,0,0);
      }
    }
    #pragma unroll
    for(int nt=0;nt<8;nt++){
      int dim = nt*16 + m;
      float bv = ba[j*128+dim];
      #pragma unroll
      for(int reg=0;reg<4;reg++)
        hb[(q*4+reg)*132 + dim] = siluf(acc[nt][reg] + bv);
    }
    __syncthreads();
    // GEMM2: z += h@Wb + bb
    const short8* Bb = (const short8*)Wbf + (size_t)j*2048 + l;
    floatx4 acc2[8];
    #pragma unroll
    for(int t=0;t<8;t++) acc2[t] = (floatx4){0.f,0.f,0.f,0.f};
    #pragma unroll
    for(int kk=0;kk<4;kk++){
      const float* hp = hb + m*132 + kk*32 + q*8;
      float4 a0 = *(const float4*)hp, a1 = *(const float4*)(hp+4);
      union { short8 s; uint32_t u[4]; } A;
      A.u[0]=packbf(a0.x,a0.y); A.u[1]=packbf(a0.z,a0.w);
      A.u[2]=packbf(a1.x,a1.y); A.u[3]=packbf(a1.z,a1.w);
      #pragma unroll
      for(int nt=0;nt<8;nt++){
        short8 bfr = Bb[(size_t)(kk*8+nt)*64];
        acc2[nt] = __builtin_amdgcn_mfma_f32_16x16x32_bf16(A.s, bfr, acc2[nt], 0,0,0);
      }
    }
    __syncthreads();
    #pragma unroll
    for(int nt=0;nt<8;nt++){
      int dim = nt*16 + m;
      float bv = bb[j*128+dim];
      #pragma unroll
      for(int reg=0;reg<4;reg++){
        int idx = (q*4+reg)*132 + dim;
        zb[idx] = zb[idx] + acc2[nt][reg] + bv;
      }
    }
    __syncthreads();
  }
  #pragma unroll
  for(int i=0;i<8;i++){
    int flat = (i*64 + l)*4;
    int node = flat>>7, k = flat&127;
    float4 v = *(float4*)(zb + node*132 + k);
    int n = n0 + node;
    *(float4*)(zi + (size_t)n*128 + k) = v;
    if(md==1){
      uint16_t* ob = (uint16_t*)outb;
      uint2 pv = make_uint2(packbf(v.x,v.y), packbf(v.z,v.w));
      *(uint2*)(ob + off1 + (long)n*st1 + k) = pv;
      if(off2 >= 0) *(uint2*)(ob + off2 + (long)n*st2 + k) = pv;
    } else {
      float* ob = (float*)outb;
      *(float4*)(ob + off1 + (long)n*st1 + k) = v;
      if(off2 >= 0) *(float4*)(ob + off2 + (long)n*st2 + k) = v;
    }
  }
}

extern "C" void kernel_launch(void* const* d_in, const int* in_sizes, int n_in,
                              void* d_out, int out_size, void* d_ws, size_t ws_size,
                              hipStream_t stream){
  const int* species = (const int*)d_in[0];
  const int* esrc    = (const int*)d_in[1];
  const int* edst    = (const int*)d_in[2];
  const void* dist   = d_in[3];
  const void* swit   = d_in[4];
  const void* Z      = d_in[5];
  const void* Ws0    = d_in[6];
  const void* bs0    = d_in[7];
  const void* V0     = d_in[8];
  const void* Ws1    = d_in[9];
  const void* bs1    = d_in[10];
  const void* V1     = d_in[11];
  const void* Wa     = d_in[12];
  const void* ba     = d_in[13];
  const void* Wb     = d_in[14];
  const void* bb     = d_in[15];

  char* ws = (char*)d_ws;
  size_t off = 0;
  auto alloc = [&](size_t bytes)->void*{ void* p = ws + off; off = (off + bytes + 255) & ~(size_t)255; return p; };
  int*      offs = (int*)     alloc((size_t)(NNODES+1)*4);
  int*      cur  = (int*)     alloc((size_t)NNODES*4);
  int*      pos  = (int*)     alloc((size_t)NEDGES*4);
  int*      dsts = (int*)     alloc((size_t)NEDGES*4);
  int*      sps  = (int*)     alloc((size_t)NEDGES*4);
  uint16_t* gs   = (uint16_t*)alloc((size_t)NEDGES*16*2);      // 12.8 MB
  float*    zi   = (float*)   alloc((size_t)NNODES*128*4);     // 10.24 MB
  uint16_t* zib  = (uint16_t*)alloc((size_t)NNODES*128*2);     // 5.12 MB
  float*    ZWs0 = (float*)   alloc((size_t)51*128*4);
  uint16_t* zfb  = (uint16_t*)alloc((size_t)51*16*2);
  float*    conv = (float*)   alloc((size_t)N_CONV*4);         // 2.04 MB
  uint16_t* Bf0  = (uint16_t*)alloc((size_t)8*8*64*8*2);       // 64 KB
  uint16_t* Bf1  = (uint16_t*)alloc((size_t)KS1*8*64*8*2);     // 557 KB
  uint16_t* Wfr  = (uint16_t*)alloc((size_t)12*16384*2);       // 384 KB (Wa L0/L1, Wb L0/L1 frags)
  int*      mode = (int*)     alloc(256);
  uint16_t* Tf   = (uint16_t*)alloc((size_t)MTILES*KS1*64*8*2); // 87.04 MB (last: largest)

  const int EB = (NEDGES+255)/256;
  hipMemsetAsync(cur, 0, NNODES*4, stream);
  k_probe<<<1,64,0,stream>>>(dist, mode);
  k_conv <<<(N_CONV+255)/256,256,0,stream>>>(V0, Ws1, bs1, V1, Wa, ba, Wb, bb, mode, conv);
  k_hist <<<EB,256,0,stream>>>(esrc, cur);
  k_scan <<<1,64,0,stream>>>(cur, offs);
  k_fill <<<EB,256,0,stream>>>(esrc, edst, species, cur, dsts, sps, pos);
  k_G    <<<EB,256,0,stream>>>(dist, swit, mode, pos, gs);
  k_spec <<<51,128,0,stream>>>(Z, Ws0, bs0, mode, ZWs0, zfb);
  k_prepB<<<(8*8*64+255)/256,256,0,stream>>>(conv+OFF_V0, 8,  Bf0);
  k_prepB<<<(64*8*64+255)/256,256,0,stream>>>(conv+OFF_V1, 64, Bf1);
  k_prepB<<<(4*8*64+255)/256,256,0,stream>>>(conv+OFF_WS1, 4, Bf1 + (size_t)64*8*64*8);
  k_prepW<<<(12*2048+255)/256,256,0,stream>>>(conv, Wfr);

  const long ZIS = (long)NNODES*128;
  uint16_t* WaF0 = Wfr;                       // Wa layer0 (3 frags)
  uint16_t* WaF1 = Wfr + (size_t)3*16384;     // Wa layer1
  uint16_t* WbF0 = Wfr + (size_t)6*16384;     // Wb layer0
  uint16_t* WbF1 = Wfr + (size_t)9*16384;     // Wb layer1

  // layer 0
  k_scat0<<<NNODES/4,256,0,stream>>>(offs, sps, gs, zfb, Tf);
  k_gemm <<<(MTILES*2+3)/4,256,0,stream>>>(Tf, Bf0, 8, species, ZWs0, (const float*)nullptr, zi);
  k_onsite<<<MTILES/2,128,0,stream>>>(zi, WaF0, conv+OFF_BA, WbF0, conv+OFF_BB,
                                      d_out, ZIS, 256, (long)-1, 0, mode);

  // layer 1
  k_packz<<<MTILES/2,128,0,stream>>>(zi, zib, Tf);
  k_scat1<<<NNODES/4,256,0,stream>>>(offs, dsts, gs, zib, Tf);
  k_gemm <<<(MTILES*2+3)/4,256,0,stream>>>(Tf, Bf1, KS1, (const int*)nullptr, (const float*)nullptr,
                                           conv+OFF_BS1, zi);
  k_onsite<<<MTILES/2,128,0,stream>>>(zi, WaF1, conv+OFF_BA+384, WbF1, conv+OFF_BB+384,
                                      d_out, ZIS+128, 256, (long)0, 128, mode);
}